// Round 6
// baseline (101.847 us; speedup 1.0000x reference)
//
#include <hip/hip_runtime.h>
#include <hip/hip_bf16.h>

// ---------------------------------------------------------------------------
// Adalibi: out[n,0,h,p*N+c] = (inv_p[n]==c) * sqrt(exp(slope_h)) / sqrt(P)
//   N=2048, H=16, P=2, k=37. Output f32, 2048*16*4096 = 134,217,728 elems.
// Single fused kernel: one block per n (2048 blocks). Each block:
//   1) redundantly counts bin changes on [1, n] (order-independent == the
//      reference cumsum), giving inv_p[n] for its own n   (~16 evals/thread)
//   2) streams its contiguous 256 KB slab (16 heads x 4096 floats) with
//      nontemporal 16B stores, nonzeros embedded via compare/select.
// No memset, no second dispatch, no inter-kernel gap.
// inv_p[n] = #{m in 1..n : ceil((t_m-u_p)/d_p) != ceil((t_{m-1}-u_p)/d_p)}
// ---------------------------------------------------------------------------

#define N_SEQ 2048
#define H_NUM 16
#define P_NUM 2

typedef float fx4 __attribute__((ext_vector_type(4)));  // nt-store-compatible

__device__ __forceinline__ int bin_idx(int kk, int m, float up, float dp) {
    // EXACT mirror of reference f32 arithmetic: ceil((t - u)/delta), t = kk+m
    return (int)ceilf(((float)(kk + m) - up) / dp);
}

__global__ __launch_bounds__(256) void fused_fill_kernel(
        const float* __restrict__ delta, const float* __restrict__ u,
        const int* __restrict__ kptr, fx4* __restrict__ out) {
    const int n   = blockIdx.x;          // 0..2047 : this block's sequence pos
    const int tid = threadIdx.x;         // 0..255
    const int kk  = kptr[0];

    __shared__ int   s_cnt[P_NUM];
    __shared__ float sval[H_NUM];

    if (tid < P_NUM) s_cnt[tid] = 0;
    if (tid < H_NUM) {
        // val_h = sqrt(exp(2^(-(h+1)/2))) / sqrt(2) (matches reference f32 path)
        const float slope = exp2f(-0.5f * (float)(tid + 1));
        sval[tid] = sqrtf(expf(slope)) * 0.70710678118f;
    }
    __syncthreads();

    // Count changes m in [1, n] for p = tid>>7 (128 threads per p).
    {
        const int p = tid >> 7;
        const float dp = delta[p], up = u[p];
        int local = 0;
        for (int m = 1 + (tid & 127); m <= n; m += 128) {
            int a = bin_idx(kk, m,     up, dp);
            int b = bin_idx(kk, m - 1, up, dp);
            local += (a != b) ? 1 : 0;
        }
        #pragma unroll
        for (int off = 32; off > 0; off >>= 1)
            local += __shfl_down(local, off, 64);
        if ((tid & 63) == 0) atomicAdd(&s_cnt[p], local);
    }
    __syncthreads();

    const int inv0 = s_cnt[0];
    const int inv1 = s_cnt[1];

    // Slab = rows (n,h=0..15), 16*4096 floats = 16384 float4, contiguous.
    fx4* __restrict__ slab = out + (size_t)n * 16384u;

    #pragma unroll 4
    for (int j = 0; j < 64; ++j) {
        const int pos  = tid + (j << 8);        // float4 index in slab, 0..16383
        const int h    = pos >> 10;             // 1024 float4 per row
        const float v  = sval[h];               // uniform per iteration
        const int col0 = (pos & 1023) << 2;     // float column 0..4092
        const int tgt  = (col0 & 2048) ? inv1 : inv0;   // p = col0>>11
        const int c    = col0 & 2047;

        fx4 o;
        o.x = (tgt == c)     ? v : 0.0f;
        o.y = (tgt == c + 1) ? v : 0.0f;
        o.z = (tgt == c + 2) ? v : 0.0f;
        o.w = (tgt == c + 3) ? v : 0.0f;
        __builtin_nontemporal_store(o, &slab[pos]);
    }
}

extern "C" void kernel_launch(void* const* d_in, const int* in_sizes, int n_in,
                              void* d_out, int out_size, void* d_ws, size_t ws_size,
                              hipStream_t stream) {
    // inputs: [0]=x (unused, dtype only), [1]=delta (P,1) f32, [2]=u (P,1) f32,
    //         [3]=seq_len (int), [4]=k (int)
    const float* delta = (const float*)d_in[1];
    const float* u     = (const float*)d_in[2];
    const int*   kptr  = (const int*)d_in[4];

    fused_fill_kernel<<<N_SEQ, 256, 0, stream>>>(delta, u, kptr, (fx4*)d_out);
}